// Round 5
// baseline (140.891 us; speedup 1.0000x reference)
//
#include <hip/hip_runtime.h>
#include <hip/hip_bf16.h>
#include <stdint.h>

#define N_ROWS 8192
#define DIM 512
#define NLAB 512
#define MARGIN_F 0.35f
#define NBLK 64                        // 8192/128 row-blocks
#define NDIAG 127                      // diag (64) + subdiag (63) tiles (mixed epilogue)
#define NTILE 2080                     // total tiles in lower triangle
#define GEMM_GRID 2176                 // 8 XCDs x 272 ranks (96 spare early-exit)
#define ROWSTAT_BLOCKS (N_ROWS / 4)    // 2048

typedef __attribute__((ext_vector_type(4))) float floatx4;
typedef __attribute__((ext_vector_type(16))) float floatx16;
typedef __attribute__((ext_vector_type(8))) int intx8;

// order-preserving float->uint map (for atomicMin/Max on floats)
__device__ __forceinline__ unsigned enc_f(float f) {
    unsigned u = __float_as_uint(f);
    return (u & 0x80000000u) ? ~u : (u | 0x80000000u);
}
__device__ __forceinline__ float dec_f(unsigned e) {
    unsigned u = (e & 0x80000000u) ? (e ^ 0x80000000u) : ~e;
    return __uint_as_float(u);
}

__device__ __forceinline__ void load_lds16(const void* g, void* l) {
    __builtin_amdgcn_global_load_lds((__attribute__((address_space(1))) void*)(void*)g,
                                     (__attribute__((address_space(3))) void*)l, 16, 0, 0);
}

// Single block: histogram of labels + exclusive scan -> offsets, zero rank counters + out.
__global__ __launch_bounds__(512) void histscan_kernel(const int* __restrict__ label,
                                                       int* __restrict__ offsetArr,
                                                       int* __restrict__ cnt,
                                                       float* __restrict__ out) {
    __shared__ int h[NLAB];
    __shared__ int sc[NLAB];
    int t = threadIdx.x;
    h[t] = 0;
    __syncthreads();
    for (int i = t; i < N_ROWS; i += 512) atomicAdd(&h[label[i]], 1);
    __syncthreads();
    int v = h[t];
    sc[t] = v;
    __syncthreads();
    for (int d = 1; d < NLAB; d <<= 1) {
        int add = (t >= d) ? sc[t - d] : 0;
        __syncthreads();
        sc[t] += add;
        __syncthreads();
    }
    offsetArr[t] = sc[t] - v;   // exclusive prefix
    cnt[t] = 0;
    if (t == 0) out[0] = 0.f;
}

// One wave per row: CE partial + fp8(e4m3) conversion scattered to label-sorted position.
// Also initializes minEnc/maxEnc.
__global__ __launch_bounds__(256) void rowstats_kernel(const float* __restrict__ x,
                                                       const int* __restrict__ label,
                                                       const int* __restrict__ offsetArr,
                                                       int* __restrict__ cnt,
                                                       unsigned char* __restrict__ a8,
                                                       int* __restrict__ sortedLabel,
                                                       float* __restrict__ cePartial,
                                                       unsigned* __restrict__ minEnc,
                                                       unsigned* __restrict__ maxEnc) {
    int gid = blockIdx.x * 256 + threadIdx.x;
    if (gid < N_ROWS) { minEnc[gid] = 0xFFFFFFFFu; maxEnc[gid] = 0u; }

    int w = threadIdx.x >> 6;
    int row = blockIdx.x * 4 + w;
    int l = threadIdx.x & 63;
    const float* xr = x + (size_t)row * DIM;
    float4 v0 = ((const float4*)xr)[2 * l];
    float4 v1 = ((const float4*)xr)[2 * l + 1];
    float vals[8] = {v0.x, v0.y, v0.z, v0.w, v1.x, v1.y, v1.z, v1.w};

    float mx = vals[0];
#pragma unroll
    for (int i = 1; i < 8; i++) mx = fmaxf(mx, vals[i]);
#pragma unroll
    for (int s = 1; s < 64; s <<= 1) mx = fmaxf(mx, __shfl_xor(mx, s, 64));

    float se = 0.f;
#pragma unroll
    for (int i = 0; i < 8; i++) se += expf(vals[i] - mx);
#pragma unroll
    for (int s = 1; s < 64; s <<= 1) se += __shfl_xor(se, s, 64);

    // sorted position for this row (counting-sort rank)
    int pos = 0;
    if (l == 0) {
        int lab = label[row];
        pos = offsetArr[lab] + atomicAdd(&cnt[lab], 1);
        sortedLabel[pos] = lab;
    }
    pos = __shfl(pos, 0, 64);

    // pack 8 fp8 e4m3 and store 8B to the sorted slot
    int w0 = __builtin_amdgcn_cvt_pk_fp8_f32(vals[0], vals[1], 0, false);
    w0 = __builtin_amdgcn_cvt_pk_fp8_f32(vals[2], vals[3], w0, true);
    int w1 = __builtin_amdgcn_cvt_pk_fp8_f32(vals[4], vals[5], 0, false);
    w1 = __builtin_amdgcn_cvt_pk_fp8_f32(vals[6], vals[7], w1, true);
    ((uint2*)(a8 + (size_t)pos * DIM))[l] = make_uint2((unsigned)w0, (unsigned)w1);

    __shared__ float wsum[4];
    if (l == 0) {
        float tl = xr[label[row]];
        wsum[w] = mx + logf(se) - tl;
    }
    __syncthreads();
    if (threadIdx.x == 0)
        cePartial[blockIdx.x] = wsum[0] + wsum[1] + wsum[2] + wsum[3];
}

// Merged GEMM on fp8. R5:
//  (1) XCD super-tiling (T1 adapted): xcd = blockIdx%8 (HW round-robin heuristic),
//      rank = blockIdx/8. XCDs 0-5 get one 16x16 off-diag super each (256 tiles,
//      2 MB working set); XCDs 6-7 get two triangular diag supers each (272 tiles,
//      2 MB). Every XCD's panels fit its private 4 MB L2 -> staging becomes
//      L2-hit. R3 evidence: FETCH_SIZE 30.9 MB = 7.7x operand (L2 thrash from
//      round-robin dispatch) -> ~900cy HBM misses the 2-deep pipeline can't hide.
//  (2) LDS tiles stored as 64 lines x 128 B (row pairs packed), chunk index
//      XOR'd with line&7 -> derived 8 words/bank = conflict-free (R0 geometry
//      measured 0; R3/R4's 64B-row variant measured 2.1M conflicts).
//  Schedule = R4's counted-vmcnt (no vmcnt(0) drains in steady state), 32x32x64
//  MX MFMA, BK=64, 32 KB dbuf, 4 blocks/CU.
__global__ __launch_bounds__(256, 4) void gemm_kernel(const unsigned char* __restrict__ A,
                                                      const int* __restrict__ sortedLabel,
                                                      unsigned* __restrict__ minEnc,
                                                      unsigned* __restrict__ maxEnc) {
    __shared__ unsigned char As[2][128 * 64];   // 2 x 8 KB (64 lines x 128 B)
    __shared__ unsigned char Bs[2][128 * 64];   // 2 x 8 KB
    __shared__ float redA[128][2], redB[128][2];       // Imx / Jmx
    __shared__ float redImn[128][2], redJmn[128][2];   // Imn / Jmn (diag only)
    __shared__ int labi[128], labj[128];               // labels (diag only)

    int b = blockIdx.x;
    int xcd = b & 7, rank = b >> 3;      // HW round-robin: b%8 -> XCD
    int bi, bj;
    if (xcd < 6) {
        if (rank >= 256) return;         // spare block (uniform per block)
        // off-diag supers: xcd -> (si,sj) in {(1,0),(2,0),(3,0),(2,1),(3,1),(3,2)}
        int sj = (xcd < 3) ? 0 : ((xcd < 5) ? 1 : 2);
        int si = (xcd < 3) ? (xcd + 1) : ((xcd < 5) ? (xcd - 1) : 3);
        bi = si * 16 + (rank >> 4);
        bj = sj * 16 + (rank & 15);
    } else {
        // diag supers: xcd6 -> supers 0,1; xcd7 -> supers 2,3 (136 tiles each)
        int s = (xcd - 6) * 2 + (rank >= 136 ? 1 : 0);
        int e = rank - (rank >= 136 ? 136 : 0);
        int r = (int)((sqrtf(8.0f * (float)e + 1.0f) - 1.0f) * 0.5f);
        while ((r + 1) * (r + 2) / 2 <= e) r++;
        while (r * (r + 1) / 2 > e) r--;
        int c = e - r * (r + 1) / 2;
        bi = s * 16 + r;
        bj = s * 16 + c;
    }
    bool diag = (bi - bj <= 1);          // mixed epilogue needed (labels can match)
    int ibase = bi * 128, jbase = bj * 128;

    int t = threadIdx.x;
    int w = t >> 6, l = t & 63;
    int wm = w >> 1, wn = w & 1;
    int cl = l & 31;        // col/row lane within a 32x32 frag
    int hi = l >> 5;        // k-half select

    // diag: label loads issued early; prologue __syncthreads publishes them.
    if (diag) {
        if (t < 128) labi[t] = sortedLabel[ibase + t];
        else labj[t - 128] = sortedLabel[jbase + t - 128];
    }

    floatx16 acc[2][2];
#pragma unroll
    for (int a = 0; a < 2; a++)
#pragma unroll
        for (int c = 0; c < 2; c++) acc[a][c] = (floatx16)0.f;

    // Staging geometry. LDS linear slot s (16 B) holds logical (row r, chunk c):
    //   line = s>>3, cc = s&7, u = cc ^ (line&7), r = 2*line + (u>>2), c = u&3
    // (tile = 64 lines x 128 B; logical row r occupies half-line (r&1)*64 B;
    //  XOR over the 8 chunk slots of a line spreads banks -> 8 words/bank.)
    int s0 = t, s1 = t + 256;
    int ln0 = s0 >> 3, u0s = (s0 & 7) ^ (ln0 & 7);
    int ln1 = s1 >> 3, u1s = (s1 & 7) ^ (ln1 & 7);
    int r0_ = 2 * ln0 + (u0s >> 2), c0_ = u0s & 3;
    int r1_ = 2 * ln1 + (u1s >> 2), c1_ = u1s & 3;
    const unsigned char* srcA0 = A + (size_t)(ibase + r0_) * DIM + c0_ * 16;
    const unsigned char* srcA1 = A + (size_t)(ibase + r1_) * DIM + c1_ * 16;
    const unsigned char* srcB0 = A + (size_t)(jbase + r0_) * DIM + c0_ * 16;
    const unsigned char* srcB1 = A + (size_t)(jbase + r1_) * DIM + c1_ * 16;
    int ldo0 = s0 * 16, ldo1 = s1 * 16;

#define STAGE(KK, BUF)                                      \
    {                                                       \
        load_lds16(srcA0 + (KK) * 64, As[BUF] + ldo0);      \
        load_lds16(srcA1 + (KK) * 64, As[BUF] + ldo1);      \
        load_lds16(srcB0 + (KK) * 64, Bs[BUF] + ldo0);      \
        load_lds16(srcB1 + (KK) * 64, Bs[BUF] + ldo1);      \
    }

// read one 32-byte fragment (rows R, k-half hi) from a swizzled tile
#define READ_FRAG(V, TILE, RR)                                      \
    {                                                               \
        int R_ = (RR);                                              \
        int line_ = R_ >> 1, g_ = line_ & 7;                        \
        int u_ = (R_ & 1) * 4 + 2 * hi;                             \
        const int4* rp_ = (const int4*)((TILE) + line_ * 128);      \
        int4 lo_ = rp_[u_ ^ g_];                                    \
        int4 h4_ = rp_[(u_ + 1) ^ g_];                              \
        V[0] = lo_.x; V[1] = lo_.y; V[2] = lo_.z; V[3] = lo_.w;     \
        V[4] = h4_.x; V[5] = h4_.y; V[6] = h4_.z; V[7] = h4_.w;     \
    }

    STAGE(0, 0);
    STAGE(1, 1);
    __syncthreads();   // one-time drain: buf0 (and labels) ready.

#pragma unroll
    for (int kk = 0; kk < 8; kk++) {
        int cur = kk & 1;

        intx8 b0, b1;
        READ_FRAG(b0, Bs[cur], wn * 64 + cl);
        READ_FRAG(b1, Bs[cur], wn * 64 + 32 + cl);
#pragma unroll
        for (int tm = 0; tm < 2; tm++) {
            intx8 a;
            READ_FRAG(a, As[cur], wm * 64 + tm * 32 + cl);
            acc[tm][0] = __builtin_amdgcn_mfma_scale_f32_32x32x64_f8f6f4(
                a, b0, acc[tm][0], 0, 0, 0, 0x7F7F7F7F, 0, 0x7F7F7F7F);
            acc[tm][1] = __builtin_amdgcn_mfma_scale_f32_32x32x64_f8f6f4(
                a, b1, acc[tm][1], 0, 0, 0, 0x7F7F7F7F, 0, 0x7F7F7F7F);
        }

        if (kk < 7) {
            __builtin_amdgcn_s_barrier();      // all waves done reading buf[cur]
            if (kk < 6) STAGE(kk + 2, cur);    // overwrite dead buffer
            if (kk < 6) {
                asm volatile("s_waitcnt vmcnt(4)" ::: "memory");   // stage(kk+1) landed
            } else {
                asm volatile("s_waitcnt vmcnt(0)" ::: "memory");   // stage(7) landed
            }
            __builtin_amdgcn_sched_barrier(0);
            __builtin_amdgcn_s_barrier();      // everyone's stage(kk+1) landed
        }
    }
#undef STAGE
#undef READ_FRAG

    // C/D layout 32x32: col = lane&31, row = (reg&3) + 8*(reg>>2) + 4*(lane>>5)
    const float INF = __builtin_inff();
    int rbase = 4 * hi;   // row contribution of the lane's k-half

    if (!diag) {
        // ---- max-only epilogue ----
        float mxJ0 = -INF, mxJ1 = -INF;
#pragma unroll
        for (int tm = 0; tm < 2; tm++) {
            float rm[16];
#pragma unroll
            for (int r = 0; r < 16; r++) {
                float v0 = acc[tm][0][r], v1 = acc[tm][1][r];
                rm[r] = fmaxf(v0, v1);
                mxJ0 = fmaxf(mxJ0, v0);
                mxJ1 = fmaxf(mxJ1, v1);
            }
#pragma unroll
            for (int r = 0; r < 16; r++)
#pragma unroll
                for (int s = 1; s < 32; s <<= 1)
                    rm[r] = fmaxf(rm[r], __shfl_xor(rm[r], s, 64));
            if (cl == 0) {
#pragma unroll
                for (int r = 0; r < 16; r++)
                    redA[wm * 64 + tm * 32 + (r & 3) + 8 * (r >> 2) + rbase][wn] = rm[r];
            }
        }
        mxJ0 = fmaxf(mxJ0, __shfl_xor(mxJ0, 32, 64));
        mxJ1 = fmaxf(mxJ1, __shfl_xor(mxJ1, 32, 64));
        if (hi == 0) {
            redB[wn * 64 + cl][wm] = mxJ0;
            redB[wn * 64 + 32 + cl][wm] = mxJ1;
        }
        __syncthreads();
        if (t < 128) {
            atomicMax(&maxEnc[ibase + t], enc_f(fmaxf(redA[t][0], redA[t][1])));
            atomicMax(&maxEnc[jbase + t], enc_f(fmaxf(redB[t][0], redB[t][1])));
        }
    } else {
        // ---- mixed epilogue (min-same / max-diff) ----
        int jl0 = labj[wn * 64 + cl];
        int jl1 = labj[wn * 64 + 32 + cl];
        float mnJ0 = INF, mnJ1 = INF, mxJ0 = -INF, mxJ1 = -INF;
#pragma unroll
        for (int tm = 0; tm < 2; tm++) {
            float rmn[16], rmx[16];
#pragma unroll
            for (int r = 0; r < 16; r++) {
                int row_l = wm * 64 + tm * 32 + (r & 3) + 8 * (r >> 2) + rbase;
                int il = labi[row_l];
                float v0 = acc[tm][0][r], v1 = acc[tm][1][r];
                bool sm0 = (jl0 == il), sm1 = (jl1 == il);
                float a0 = sm0 ? v0 : INF, d0 = sm0 ? -INF : v0;
                float a1 = sm1 ? v1 : INF, d1 = sm1 ? -INF : v1;
                rmn[r] = fminf(a0, a1);
                rmx[r] = fmaxf(d0, d1);
                mnJ0 = fminf(mnJ0, a0); mxJ0 = fmaxf(mxJ0, d0);
                mnJ1 = fminf(mnJ1, a1); mxJ1 = fmaxf(mxJ1, d1);
            }
#pragma unroll
            for (int r = 0; r < 16; r++)
#pragma unroll
                for (int s = 1; s < 32; s <<= 1) {
                    rmn[r] = fminf(rmn[r], __shfl_xor(rmn[r], s, 64));
                    rmx[r] = fmaxf(rmx[r], __shfl_xor(rmx[r], s, 64));
                }
            if (cl == 0) {
#pragma unroll
                for (int r = 0; r < 16; r++) {
                    int row_l = wm * 64 + tm * 32 + (r & 3) + 8 * (r >> 2) + rbase;
                    redImn[row_l][wn] = rmn[r];
                    redA[row_l][wn] = rmx[r];
                }
            }
        }
        mnJ0 = fminf(mnJ0, __shfl_xor(mnJ0, 32, 64));
        mnJ1 = fminf(mnJ1, __shfl_xor(mnJ1, 32, 64));
        mxJ0 = fmaxf(mxJ0, __shfl_xor(mxJ0, 32, 64));
        mxJ1 = fmaxf(mxJ1, __shfl_xor(mxJ1, 32, 64));
        if (hi == 0) {
            redJmn[wn * 64 + cl][wm] = mnJ0;
            redJmn[wn * 64 + 32 + cl][wm] = mnJ1;
            redB[wn * 64 + cl][wm] = mxJ0;
            redB[wn * 64 + 32 + cl][wm] = mxJ1;
        }
        __syncthreads();
        if (t < 128) {
            atomicMin(&minEnc[ibase + t], enc_f(fminf(redImn[t][0], redImn[t][1])));
            atomicMax(&maxEnc[ibase + t], enc_f(fmaxf(redA[t][0], redA[t][1])));
            atomicMin(&minEnc[jbase + t], enc_f(fminf(redJmn[t][0], redJmn[t][1])));
            atomicMax(&maxEnc[jbase + t], enc_f(fmaxf(redB[t][0], redB[t][1])));
        }
    }
}

// 32 blocks; one float atomicAdd per block into pre-zeroed out[0].
__global__ __launch_bounds__(256) void finalize_kernel(const unsigned* __restrict__ minEnc,
                                                       const unsigned* __restrict__ maxEnc,
                                                       const float* __restrict__ cePartial,
                                                       float* __restrict__ out) {
    int gid = blockIdx.x * 256 + threadIdx.x;   // 8192 threads total
    float mn = dec_f(minEnc[gid]);
    float mxv = dec_f(maxEnc[gid]);
    // pos - neg = 2*(max_diff G - min_same G); sq_i cancels, sq_j ≈ 1 (dev ~1e-7)
    float s = fmaxf(2.0f * (mxv - mn) + MARGIN_F, 0.f);
    if (gid < ROWSTAT_BLOCKS) s += cePartial[gid];
#pragma unroll
    for (int sh = 1; sh < 64; sh <<= 1) s += __shfl_xor(s, sh, 64);
    __shared__ float red[4];
    int w = threadIdx.x >> 6, l = threadIdx.x & 63;
    if (l == 0) red[w] = s;
    __syncthreads();
    if (threadIdx.x == 0)
        atomicAdd(out, (red[0] + red[1] + red[2] + red[3]) * (1.0f / (float)N_ROWS));
}

extern "C" void kernel_launch(void* const* d_in, const int* in_sizes, int n_in,
                              void* d_out, int out_size, void* d_ws, size_t ws_size,
                              hipStream_t stream) {
    const float* x = (const float*)d_in[0];
    const int* label = (const int*)d_in[1];
    float* out = (float*)d_out;

    char* ws = (char*)d_ws;
    unsigned char* a8 = (unsigned char*)ws;                      // 4 MB fp8 sorted copy
    char* p = ws + (size_t)N_ROWS * DIM;
    unsigned* minEnc = (unsigned*)p;            p += N_ROWS * 4;
    unsigned* maxEnc = (unsigned*)p;            p += N_ROWS * 4;
    float* cePartial = (float*)p;               p += ROWSTAT_BLOCKS * 4;
    int* offsetArr = (int*)p;                   p += NLAB * 4;
    int* cnt = (int*)p;                         p += NLAB * 4;
    int* sortedLabel = (int*)p;                 p += N_ROWS * 4;

    histscan_kernel<<<1, 512, 0, stream>>>(label, offsetArr, cnt, out);
    rowstats_kernel<<<ROWSTAT_BLOCKS, 256, 0, stream>>>(x, label, offsetArr, cnt, a8,
                                                        sortedLabel, cePartial, minEnc, maxEnc);
    gemm_kernel<<<GEMM_GRID, 256, 0, stream>>>(a8, sortedLabel, minEnc, maxEnc);
    finalize_kernel<<<32, 256, 0, stream>>>(minEnc, maxEnc, cePartial, out);
}

// Round 6
// 118.143 us; speedup vs baseline: 1.1925x; 1.1925x over previous
//
#include <hip/hip_runtime.h>
#include <hip/hip_bf16.h>
#include <stdint.h>

#define N_ROWS 8192
#define DIM 512
#define NLAB 512
#define MARGIN_F 0.35f
#define NBLK 64                        // 8192/128 row-blocks
#define NPURE 1953                     // tiles with bi-bj >= 2
#define NDIAG 127                      // diagonal (64) + subdiagonal (63)
#define NTILE (NPURE + NDIAG)          // 2080
#define ROWSTAT_BLOCKS (N_ROWS / 4)    // 2048

typedef __attribute__((ext_vector_type(4))) float floatx4;
typedef __attribute__((ext_vector_type(16))) float floatx16;
typedef __attribute__((ext_vector_type(8))) int intx8;

// order-preserving float->uint map (for atomicMin/Max on floats)
__device__ __forceinline__ unsigned enc_f(float f) {
    unsigned u = __float_as_uint(f);
    return (u & 0x80000000u) ? ~u : (u | 0x80000000u);
}
__device__ __forceinline__ float dec_f(unsigned e) {
    unsigned u = (e & 0x80000000u) ? (e ^ 0x80000000u) : ~e;
    return __uint_as_float(u);
}

__device__ __forceinline__ void load_lds16(const void* g, void* l) {
    __builtin_amdgcn_global_load_lds((__attribute__((address_space(1))) void*)(void*)g,
                                     (__attribute__((address_space(3))) void*)l, 16, 0, 0);
}

// Single block: histogram of labels + exclusive scan -> offsets, zero rank counters + out.
__global__ __launch_bounds__(512) void histscan_kernel(const int* __restrict__ label,
                                                       int* __restrict__ offsetArr,
                                                       int* __restrict__ cnt,
                                                       float* __restrict__ out) {
    __shared__ int h[NLAB];
    __shared__ int sc[NLAB];
    int t = threadIdx.x;
    h[t] = 0;
    __syncthreads();
    for (int i = t; i < N_ROWS; i += 512) atomicAdd(&h[label[i]], 1);
    __syncthreads();
    int v = h[t];
    sc[t] = v;
    __syncthreads();
    for (int d = 1; d < NLAB; d <<= 1) {
        int add = (t >= d) ? sc[t - d] : 0;
        __syncthreads();
        sc[t] += add;
        __syncthreads();
    }
    offsetArr[t] = sc[t] - v;   // exclusive prefix
    cnt[t] = 0;
    if (t == 0) out[0] = 0.f;
}

// One wave per row: CE partial + fp8(e4m3) conversion scattered to label-sorted position.
// Also initializes minEnc/maxEnc.
__global__ __launch_bounds__(256) void rowstats_kernel(const float* __restrict__ x,
                                                       const int* __restrict__ label,
                                                       const int* __restrict__ offsetArr,
                                                       int* __restrict__ cnt,
                                                       unsigned char* __restrict__ a8,
                                                       int* __restrict__ sortedLabel,
                                                       float* __restrict__ cePartial,
                                                       unsigned* __restrict__ minEnc,
                                                       unsigned* __restrict__ maxEnc) {
    int gid = blockIdx.x * 256 + threadIdx.x;
    if (gid < N_ROWS) { minEnc[gid] = 0xFFFFFFFFu; maxEnc[gid] = 0u; }

    int w = threadIdx.x >> 6;
    int row = blockIdx.x * 4 + w;
    int l = threadIdx.x & 63;
    const float* xr = x + (size_t)row * DIM;
    float4 v0 = ((const float4*)xr)[2 * l];
    float4 v1 = ((const float4*)xr)[2 * l + 1];
    float vals[8] = {v0.x, v0.y, v0.z, v0.w, v1.x, v1.y, v1.z, v1.w};

    float mx = vals[0];
#pragma unroll
    for (int i = 1; i < 8; i++) mx = fmaxf(mx, vals[i]);
#pragma unroll
    for (int s = 1; s < 64; s <<= 1) mx = fmaxf(mx, __shfl_xor(mx, s, 64));

    float se = 0.f;
#pragma unroll
    for (int i = 0; i < 8; i++) se += expf(vals[i] - mx);
#pragma unroll
    for (int s = 1; s < 64; s <<= 1) se += __shfl_xor(se, s, 64);

    // sorted position for this row (counting-sort rank)
    int pos = 0;
    if (l == 0) {
        int lab = label[row];
        pos = offsetArr[lab] + atomicAdd(&cnt[lab], 1);
        sortedLabel[pos] = lab;
    }
    pos = __shfl(pos, 0, 64);

    // pack 8 fp8 e4m3 and store 8B to the sorted slot
    int w0 = __builtin_amdgcn_cvt_pk_fp8_f32(vals[0], vals[1], 0, false);
    w0 = __builtin_amdgcn_cvt_pk_fp8_f32(vals[2], vals[3], w0, true);
    int w1 = __builtin_amdgcn_cvt_pk_fp8_f32(vals[4], vals[5], 0, false);
    w1 = __builtin_amdgcn_cvt_pk_fp8_f32(vals[6], vals[7], w1, true);
    ((uint2*)(a8 + (size_t)pos * DIM))[l] = make_uint2((unsigned)w0, (unsigned)w1);

    __shared__ float wsum[4];
    if (l == 0) {
        float tl = xr[label[row]];
        wsum[w] = mx + logf(se) - tl;
    }
    __syncthreads();
    if (threadIdx.x == 0)
        cePartial[blockIdx.x] = wsum[0] + wsum[1] + wsum[2] + wsum[3];
}

// Merged GEMM on fp8. R6 = R4 structure with the SPILL FIX:
//   __launch_bounds__(256,3) not (256,4). gfx950 has a UNIFIED VGPR/AGPR file:
//   (256,4) caps total at 128; acc (floatx16[2][2]) owns 64 AGPR -> only 64
//   arch VGPRs for ~70 live values -> the K-loop spilled to scratch, putting a
//   ~200cy scratch round-trip inside every MFMA chain. Counters: R3/R4/R5 all
//   VGPR_Count=64 (the tell); R0 used (256,3)/84 regs for exactly this reason
//   (its comment warned; rounds 3-5 repeated the documented failure).
//   At (256,3): arch budget ~106, LDS 37.9KB -> 3 blocks/CU (= R0 occupancy).
// Structure (unchanged from R4): 32x32x64 MX MFMA, BK=64, 32KB dbuf, counted
// vmcnt (no vmcnt(0) drain in steady state), linear tile order.
__global__ __launch_bounds__(256, 3) void gemm_kernel(const unsigned char* __restrict__ A,
                                                      const int* __restrict__ sortedLabel,
                                                      unsigned* __restrict__ minEnc,
                                                      unsigned* __restrict__ maxEnc) {
    __shared__ unsigned char As[2][128 * 64];   // 2 x 8 KB
    __shared__ unsigned char Bs[2][128 * 64];   // 2 x 8 KB
    __shared__ float redA[128][2], redB[128][2];       // Imx / Jmx
    __shared__ float redImn[128][2], redJmn[128][2];   // Imn / Jmn (diag only)
    __shared__ int labi[128], labj[128];               // labels (diag only)

    int b = blockIdx.x;
    bool diag = (b < NDIAG);
    int bi, bj;
    if (diag) {
        bi = (b < 64) ? b : (b - 63);
        bj = (b < 64) ? b : (b - 64);
    } else {
        int p = b - NDIAG;
        int ci = (int)((sqrtf(8.0f * (float)p + 1.0f) - 1.0f) * 0.5f);
        while ((ci + 1) * (ci + 2) / 2 <= p) ci++;
        while (ci * (ci + 1) / 2 > p) ci--;
        bj = p - ci * (ci + 1) / 2;
        bi = ci + 2;
    }
    int ibase = bi * 128, jbase = bj * 128;

    int t = threadIdx.x;
    int w = t >> 6, l = t & 63;
    int wm = w >> 1, wn = w & 1;
    int cl = l & 31;        // col/row lane within a 32x32 frag
    int hi = l >> 5;        // k-half select

    // diag: label loads issued early; prologue __syncthreads publishes them.
    if (diag) {
        if (t < 128) labi[t] = sortedLabel[ibase + t];
        else labj[t - 128] = sortedLabel[jbase + t - 128];
    }

    floatx16 acc[2][2];
#pragma unroll
    for (int a = 0; a < 2; a++)
#pragma unroll
        for (int c = 0; c < 2; c++) acc[a][c] = (floatx16)0.f;

    // Staging geometry: slot s = t + 256*i covers 512 slots of 16B = 8 KB tile.
    // LDS layout linear (gl_lds requirement); SOURCE pre-swizzled so that the
    // stored chunk at row r, slot c holds logical chunk c ^ ((r>>1)&3).
    int s0 = t, s1 = t + 256;
    int r0_ = s0 >> 2, r1_ = s1 >> 2;
    int c0_ = (s0 & 3) ^ ((r0_ >> 1) & 3);
    int c1_ = (s1 & 3) ^ ((r1_ >> 1) & 3);
    const unsigned char* srcA0 = A + (size_t)(ibase + r0_) * DIM + c0_ * 16;
    const unsigned char* srcA1 = A + (size_t)(ibase + r1_) * DIM + c1_ * 16;
    const unsigned char* srcB0 = A + (size_t)(jbase + r0_) * DIM + c0_ * 16;
    const unsigned char* srcB1 = A + (size_t)(jbase + r1_) * DIM + c1_ * 16;
    int ldo0 = s0 * 16, ldo1 = s1 * 16;

#define STAGE(KK, BUF)                                      \
    {                                                       \
        load_lds16(srcA0 + (KK) * 64, As[BUF] + ldo0);      \
        load_lds16(srcA1 + (KK) * 64, As[BUF] + ldo1);      \
        load_lds16(srcB0 + (KK) * 64, Bs[BUF] + ldo0);      \
        load_lds16(srcB1 + (KK) * 64, Bs[BUF] + ldo1);      \
    }

    STAGE(0, 0);
    STAGE(1, 1);
    __syncthreads();   // one-time drain: buf0 (and labels) ready.

#pragma unroll
    for (int kk = 0; kk < 8; kk++) {
        int cur = kk & 1;

        // B fragments: lane holds col cl of j-rows, k = hi*32..hi*32+31 (2 chunks)
        intx8 b0, b1;
        {
            int r = wn * 64 + cl;
            int f = (r >> 1) & 3;
            const int4* rp = (const int4*)(Bs[cur] + r * 64);
            int4 lo = rp[(2 * hi) ^ f];
            int4 h4 = rp[(2 * hi + 1) ^ f];
            b0[0] = lo.x; b0[1] = lo.y; b0[2] = lo.z; b0[3] = lo.w;
            b0[4] = h4.x; b0[5] = h4.y; b0[6] = h4.z; b0[7] = h4.w;
        }
        {
            int r = wn * 64 + 32 + cl;
            int f = (r >> 1) & 3;
            const int4* rp = (const int4*)(Bs[cur] + r * 64);
            int4 lo = rp[(2 * hi) ^ f];
            int4 h4 = rp[(2 * hi + 1) ^ f];
            b1[0] = lo.x; b1[1] = lo.y; b1[2] = lo.z; b1[3] = lo.w;
            b1[4] = h4.x; b1[5] = h4.y; b1[6] = h4.z; b1[7] = h4.w;
        }
#pragma unroll
        for (int tm = 0; tm < 2; tm++) {
            int r = wm * 64 + tm * 32 + cl;
            int f = (r >> 1) & 3;
            const int4* rp = (const int4*)(As[cur] + r * 64);
            int4 lo = rp[(2 * hi) ^ f];
            int4 h4 = rp[(2 * hi + 1) ^ f];
            intx8 a;
            a[0] = lo.x; a[1] = lo.y; a[2] = lo.z; a[3] = lo.w;
            a[4] = h4.x; a[5] = h4.y; a[6] = h4.z; a[7] = h4.w;
            acc[tm][0] = __builtin_amdgcn_mfma_scale_f32_32x32x64_f8f6f4(
                a, b0, acc[tm][0], 0, 0, 0, 0x7F7F7F7F, 0, 0x7F7F7F7F);
            acc[tm][1] = __builtin_amdgcn_mfma_scale_f32_32x32x64_f8f6f4(
                a, b1, acc[tm][1], 0, 0, 0, 0x7F7F7F7F, 0, 0x7F7F7F7F);
        }

        if (kk < 7) {
            __builtin_amdgcn_s_barrier();      // all waves done reading buf[cur]
            if (kk < 6) STAGE(kk + 2, cur);    // overwrite dead buffer
            if (kk < 6) {
                asm volatile("s_waitcnt vmcnt(4)" ::: "memory");   // stage(kk+1) landed
            } else {
                asm volatile("s_waitcnt vmcnt(0)" ::: "memory");   // stage(7) landed
            }
            __builtin_amdgcn_sched_barrier(0);
            __builtin_amdgcn_s_barrier();      // everyone's stage(kk+1) landed
        }
    }
#undef STAGE

    // C/D layout 32x32: col = lane&31, row = (reg&3) + 8*(reg>>2) + 4*(lane>>5)
    const float INF = __builtin_inff();
    int rbase = 4 * hi;   // row contribution of the lane's k-half

    if (!diag) {
        // ---- max-only epilogue ----
        float mxJ0 = -INF, mxJ1 = -INF;
#pragma unroll
        for (int tm = 0; tm < 2; tm++) {
            float rm[16];
#pragma unroll
            for (int r = 0; r < 16; r++) {
                float v0 = acc[tm][0][r], v1 = acc[tm][1][r];
                rm[r] = fmaxf(v0, v1);
                mxJ0 = fmaxf(mxJ0, v0);
                mxJ1 = fmaxf(mxJ1, v1);
            }
#pragma unroll
            for (int r = 0; r < 16; r++)
#pragma unroll
                for (int s = 1; s < 32; s <<= 1)
                    rm[r] = fmaxf(rm[r], __shfl_xor(rm[r], s, 64));
            if (cl == 0) {
#pragma unroll
                for (int r = 0; r < 16; r++)
                    redA[wm * 64 + tm * 32 + (r & 3) + 8 * (r >> 2) + rbase][wn] = rm[r];
            }
        }
        mxJ0 = fmaxf(mxJ0, __shfl_xor(mxJ0, 32, 64));
        mxJ1 = fmaxf(mxJ1, __shfl_xor(mxJ1, 32, 64));
        if (hi == 0) {
            redB[wn * 64 + cl][wm] = mxJ0;
            redB[wn * 64 + 32 + cl][wm] = mxJ1;
        }
        __syncthreads();
        if (t < 128) {
            atomicMax(&maxEnc[ibase + t], enc_f(fmaxf(redA[t][0], redA[t][1])));
            atomicMax(&maxEnc[jbase + t], enc_f(fmaxf(redB[t][0], redB[t][1])));
        }
    } else {
        // ---- mixed epilogue (min-same / max-diff) ----
        int jl0 = labj[wn * 64 + cl];
        int jl1 = labj[wn * 64 + 32 + cl];
        float mnJ0 = INF, mnJ1 = INF, mxJ0 = -INF, mxJ1 = -INF;
#pragma unroll
        for (int tm = 0; tm < 2; tm++) {
            float rmn[16], rmx[16];
#pragma unroll
            for (int r = 0; r < 16; r++) {
                int row_l = wm * 64 + tm * 32 + (r & 3) + 8 * (r >> 2) + rbase;
                int il = labi[row_l];
                float v0 = acc[tm][0][r], v1 = acc[tm][1][r];
                bool sm0 = (jl0 == il), sm1 = (jl1 == il);
                float a0 = sm0 ? v0 : INF, d0 = sm0 ? -INF : v0;
                float a1 = sm1 ? v1 : INF, d1 = sm1 ? -INF : v1;
                rmn[r] = fminf(a0, a1);
                rmx[r] = fmaxf(d0, d1);
                mnJ0 = fminf(mnJ0, a0); mxJ0 = fmaxf(mxJ0, d0);
                mnJ1 = fminf(mnJ1, a1); mxJ1 = fmaxf(mxJ1, d1);
            }
#pragma unroll
            for (int r = 0; r < 16; r++)
#pragma unroll
                for (int s = 1; s < 32; s <<= 1) {
                    rmn[r] = fminf(rmn[r], __shfl_xor(rmn[r], s, 64));
                    rmx[r] = fmaxf(rmx[r], __shfl_xor(rmx[r], s, 64));
                }
            if (cl == 0) {
#pragma unroll
                for (int r = 0; r < 16; r++) {
                    int row_l = wm * 64 + tm * 32 + (r & 3) + 8 * (r >> 2) + rbase;
                    redImn[row_l][wn] = rmn[r];
                    redA[row_l][wn] = rmx[r];
                }
            }
        }
        mnJ0 = fminf(mnJ0, __shfl_xor(mnJ0, 32, 64));
        mnJ1 = fminf(mnJ1, __shfl_xor(mnJ1, 32, 64));
        mxJ0 = fmaxf(mxJ0, __shfl_xor(mxJ0, 32, 64));
        mxJ1 = fmaxf(mxJ1, __shfl_xor(mxJ1, 32, 64));
        if (hi == 0) {
            redJmn[wn * 64 + cl][wm] = mnJ0;
            redJmn[wn * 64 + 32 + cl][wm] = mnJ1;
            redB[wn * 64 + cl][wm] = mxJ0;
            redB[wn * 64 + 32 + cl][wm] = mxJ1;
        }
        __syncthreads();
        if (t < 128) {
            atomicMin(&minEnc[ibase + t], enc_f(fminf(redImn[t][0], redImn[t][1])));
            atomicMax(&maxEnc[ibase + t], enc_f(fmaxf(redA[t][0], redA[t][1])));
            atomicMin(&minEnc[jbase + t], enc_f(fminf(redJmn[t][0], redJmn[t][1])));
            atomicMax(&maxEnc[jbase + t], enc_f(fmaxf(redB[t][0], redB[t][1])));
        }
    }
}

// 32 blocks; one float atomicAdd per block into pre-zeroed out[0].
__global__ __launch_bounds__(256) void finalize_kernel(const unsigned* __restrict__ minEnc,
                                                       const unsigned* __restrict__ maxEnc,
                                                       const float* __restrict__ cePartial,
                                                       float* __restrict__ out) {
    int gid = blockIdx.x * 256 + threadIdx.x;   // 8192 threads total
    float mn = dec_f(minEnc[gid]);
    float mxv = dec_f(maxEnc[gid]);
    // pos - neg = 2*(max_diff G - min_same G); sq_i cancels, sq_j ≈ 1 (dev ~1e-7)
    float s = fmaxf(2.0f * (mxv - mn) + MARGIN_F, 0.f);
    if (gid < ROWSTAT_BLOCKS) s += cePartial[gid];
#pragma unroll
    for (int sh = 1; sh < 64; sh <<= 1) s += __shfl_xor(s, sh, 64);
    __shared__ float red[4];
    int w = threadIdx.x >> 6, l = threadIdx.x & 63;
    if (l == 0) red[w] = s;
    __syncthreads();
    if (threadIdx.x == 0)
        atomicAdd(out, (red[0] + red[1] + red[2] + red[3]) * (1.0f / (float)N_ROWS));
}

extern "C" void kernel_launch(void* const* d_in, const int* in_sizes, int n_in,
                              void* d_out, int out_size, void* d_ws, size_t ws_size,
                              hipStream_t stream) {
    const float* x = (const float*)d_in[0];
    const int* label = (const int*)d_in[1];
    float* out = (float*)d_out;

    char* ws = (char*)d_ws;
    unsigned char* a8 = (unsigned char*)ws;                      // 4 MB fp8 sorted copy
    char* p = ws + (size_t)N_ROWS * DIM;
    unsigned* minEnc = (unsigned*)p;            p += N_ROWS * 4;
    unsigned* maxEnc = (unsigned*)p;            p += N_ROWS * 4;
    float* cePartial = (float*)p;               p += ROWSTAT_BLOCKS * 4;
    int* offsetArr = (int*)p;                   p += NLAB * 4;
    int* cnt = (int*)p;                         p += NLAB * 4;
    int* sortedLabel = (int*)p;                 p += N_ROWS * 4;

    histscan_kernel<<<1, 512, 0, stream>>>(label, offsetArr, cnt, out);
    rowstats_kernel<<<ROWSTAT_BLOCKS, 256, 0, stream>>>(x, label, offsetArr, cnt, a8,
                                                        sortedLabel, cePartial, minEnc, maxEnc);
    gemm_kernel<<<NTILE, 256, 0, stream>>>(a8, sortedLabel, minEnc, maxEnc);
    finalize_kernel<<<32, 256, 0, stream>>>(minEnc, maxEnc, cePartial, out);
}